// Round 8
// baseline (1742.431 us; speedup 1.0000x reference)
//
#include <hip/hip_runtime.h>
#include <hip/hip_cooperative_groups.h>

namespace cg = cooperative_groups;

// LightGCN 3-layer propagation — R8: pre-scaled bf16 mirror (edge record = bare
// src id) + single cooperative kernel for init/prop1-3/epilogue.
//
// R7 post-mortem: bf16 gather (half bytes) gave only -65us -> props are
// request-rate/latency bound, not byte bound. Scatter's 8B random writes and
// 13 launches still cost. R8: (a) y_l = dinv*x_l stored bf16 -> srw becomes
// int (scatter RMW traffic halves), w multiply leaves inner loop;
// (b) coop-fused main phase: fewer launches + visible aggregate counters.

static constexpr int NUSERS = 500000;
static constexpr int NITEMS = 200000;
static constexpr int NNODES = 700000;   // NUSERS + NITEMS
static constexpr int NE     = 5000000;
static constexpr int SCAN_B = 1024;
static constexpr int NSB    = (NNODES + SCAN_B - 1) / SCAN_B;   // 684 scan blocks

typedef float f4 __attribute__((ext_vector_type(4)));   // native vec for nt ops

// round-to-nearest-even fp32 -> bf16 (as uint16 in low bits)
__device__ inline unsigned bf16rne(float f) {
    unsigned u = __float_as_uint(f);
    return (u + 0x7FFFu + ((u >> 16) & 1u)) >> 16;
}
__device__ inline unsigned packbf(float lo, float hi) {
    return bf16rne(lo) | (bf16rne(hi) << 16);
}
__device__ inline void acc8(float4& A, float4& B, uint4 q) {
    A.x += __uint_as_float(q.x << 16); A.y += __uint_as_float(q.x & 0xFFFF0000u);
    A.z += __uint_as_float(q.y << 16); A.w += __uint_as_float(q.y & 0xFFFF0000u);
    B.x += __uint_as_float(q.z << 16); B.y += __uint_as_float(q.z & 0xFFFF0000u);
    B.z += __uint_as_float(q.w << 16); B.w += __uint_as_float(q.w & 0xFFFF0000u);
}

// ===================== sort pipeline (unchanged structure) ====================
__global__ void k_hist(const int* __restrict__ col, int* __restrict__ deg) {
    int e = blockIdx.x * blockDim.x + threadIdx.x;
    if (e < NE) atomicAdd(&deg[col[e]], 1);
}

__global__ void k_scan1(const int* __restrict__ deg, int* __restrict__ offs,
                        int* __restrict__ bsums) {
    __shared__ int s[SCAN_B];
    int t = threadIdx.x;
    int i = blockIdx.x * SCAN_B + t;
    int v = (i < NNODES) ? deg[i] : 0;
    s[t] = v;
    __syncthreads();
    for (int off = 1; off < SCAN_B; off <<= 1) {
        int add = (t >= off) ? s[t - off] : 0;
        __syncthreads();
        s[t] += add;
        __syncthreads();
    }
    if (i < NNODES) offs[i] = s[t] - v;
    if (t == SCAN_B - 1) bsums[blockIdx.x] = s[t];
}

__global__ void k_scan2(int* __restrict__ bsums) {
    __shared__ int s[SCAN_B];
    int t = threadIdx.x;
    int v = (t < NSB) ? bsums[t] : 0;
    s[t] = v;
    __syncthreads();
    for (int off = 1; off < SCAN_B; off <<= 1) {
        int add = (t >= off) ? s[t - off] : 0;
        __syncthreads();
        s[t] += add;
        __syncthreads();
    }
    if (t < NSB) bsums[t] = s[t] - v;
}

__global__ void k_scan3(int* __restrict__ offs, const int* __restrict__ bsums,
                        int* __restrict__ cursor, const int* __restrict__ deg,
                        float* __restrict__ dinv) {
    int i = blockIdx.x * blockDim.x + threadIdx.x;
    if (i < NNODES) {
        int o = offs[i] + bsums[i >> 10];
        offs[i]   = o;
        cursor[i] = o;
        int d = deg[i];
        dinv[i] = (d > 0) ? rsqrtf((float)d) : 0.0f;
    }
    if (i == 0) offs[NNODES] = NE;
}

__global__ void k_dcount(const int* __restrict__ deg, int* __restrict__ dcnt) {
    __shared__ int h[256];
    int t = threadIdx.x;
    h[t] = 0;
    __syncthreads();
    for (int n = blockIdx.x * blockDim.x + t; n < NNODES; n += gridDim.x * blockDim.x)
        atomicAdd(&h[min(deg[n], 255)], 1);
    __syncthreads();
    if (h[t]) atomicAdd(&dcnt[t], h[t]);
}

__global__ void k_dscan(const int* __restrict__ dcnt, int* __restrict__ dcur) {
    __shared__ int s[256];
    int t = threadIdx.x;
    int v = dcnt[t];
    s[t] = v;
    __syncthreads();
    for (int off = 1; off < 256; off <<= 1) {
        int add = (t >= off) ? s[t - off] : 0;
        __syncthreads();
        s[t] += add;
        __syncthreads();
    }
    dcur[t] = s[t] - v;
}

__global__ void k_dscatter(const int* __restrict__ deg, int* __restrict__ dcur,
                           int* __restrict__ perm) {
    __shared__ int lcnt[256];
    __shared__ int lbase[256];
    int t = threadIdx.x;
    lcnt[t] = 0;
    __syncthreads();
    int n = blockIdx.x * 256 + t;
    int bucket = 0, lrank = 0;
    if (n < NNODES) {
        bucket = min(deg[n], 255);
        lrank = atomicAdd(&lcnt[bucket], 1);
    }
    __syncthreads();
    if (lcnt[t]) lbase[t] = atomicAdd(&dcur[t], lcnt[t]);
    __syncthreads();
    if (n < NNODES) perm[lbase[bucket] + lrank] = n;
}

// edge scatter: record is just the source id now (4 B)
__global__ void k_scatter(const int* __restrict__ row, const int* __restrict__ col,
                          int* __restrict__ cursor, int* __restrict__ sr) {
    int e = blockIdx.x * blockDim.x + threadIdx.x;
    if (e >= NE) return;
    int r = row[e], c = col[e];
    int pos = atomicAdd(&cursor[c], 1);
    sr[pos] = r;
}

// ===================== fused main phase (cooperative) =========================
// phase 0: x0 = concat(user,item) fp32; y0 = dinv*x0 bf16 mirror
// phase L=1..3: acc = sum of gathered y_{L-1}; x_L = dinv*acc (fp32);
//               y_L = dinv^2*acc (bf16, L<3); L==3 epilogue: mean outputs.
__global__ void __launch_bounds__(256, 4) k_fused(
    const float4* __restrict__ user, const float4* __restrict__ item,
    const int* __restrict__ perm, const int* __restrict__ offs,
    const int* __restrict__ sr, const float* __restrict__ dinv,
    uint4* __restrict__ xb0, uint4* __restrict__ xb1,
    float4* __restrict__ all_emb,
    float* __restrict__ out_users, float* __restrict__ out_items)
{
    cg::grid_group grid = cg::this_grid();
    const int stride = gridDim.x * blockDim.x;
    const int total  = NNODES * 8;
    const int tid0   = blockIdx.x * blockDim.x + threadIdx.x;

    // ---- phase 0: init ----
    for (int idx = tid0; idx < total; idx += stride) {
        int n = idx >> 3, lane = idx & 7;
        const float4* s = ((n < NUSERS) ? user + (size_t)n * 16
                                        : item + (size_t)(n - NUSERS) * 16) + lane * 2;
        float4 a = s[0], b = s[1];
        float4* dst = all_emb + (size_t)n * 64 + lane * 2;
        dst[0] = a; dst[1] = b;
        float dv = dinv[n];
        uint4 o;
        o.x = packbf(dv * a.x, dv * a.y); o.y = packbf(dv * a.z, dv * a.w);
        o.z = packbf(dv * b.x, dv * b.y); o.w = packbf(dv * b.z, dv * b.w);
        xb0[(size_t)n * 8 + lane] = o;
    }
    grid.sync();

    // ---- phases 1..3 ----
    #pragma unroll 1
    for (int L = 1; L <= 3; ++L) {
        const uint4* xbp = (L == 2) ? xb1 : xb0;   // src mirror
        uint4*       xbc = (L == 1) ? xb1 : xb0;   // dst mirror (unused L==3)
        for (int idx = tid0; idx < total; idx += stride) {
            int g = idx >> 3, lane = idx & 7;
            int n = perm[g];
            int b = offs[n], e = offs[n + 1];
            float4 accA = make_float4(0.f, 0.f, 0.f, 0.f);
            float4 accB = make_float4(0.f, 0.f, 0.f, 0.f);
            const uint4* src = xbp + lane;
            int k = b;
            for (; k + 4 <= e; k += 4) {
                int r0 = sr[k + 0], r1 = sr[k + 1], r2 = sr[k + 2], r3 = sr[k + 3];
                uint4 q0 = src[(size_t)r0 * 8];
                uint4 q1 = src[(size_t)r1 * 8];
                uint4 q2 = src[(size_t)r2 * 8];
                uint4 q3 = src[(size_t)r3 * 8];
                acc8(accA, accB, q0); acc8(accA, accB, q1);
                acc8(accA, accB, q2); acc8(accA, accB, q3);
            }
            for (; k < e; ++k) {
                uint4 q = src[(size_t)sr[k] * 8];
                acc8(accA, accB, q);
            }
            float dv = dinv[n];
            accA.x *= dv; accA.y *= dv; accA.z *= dv; accA.w *= dv;
            accB.x *= dv; accB.y *= dv; accB.z *= dv; accB.w *= dv;

            float4* dst = all_emb + (size_t)n * 64 + L * 16 + lane * 2;
            if (L < 3) {
                dst[0] = accA;
                dst[1] = accB;
                uint4 o;
                o.x = packbf(dv * accA.x, dv * accA.y);
                o.y = packbf(dv * accA.z, dv * accA.w);
                o.z = packbf(dv * accB.x, dv * accB.y);
                o.w = packbf(dv * accB.z, dv * accB.w);
                xbc[(size_t)n * 8 + lane] = o;
            } else {
                const f4* p = reinterpret_cast<const f4*>(all_emb + (size_t)n * 64 + lane * 2);
                f4 x0a = __builtin_nontemporal_load(p + 0);
                f4 x0b = __builtin_nontemporal_load(p + 1);
                f4 x1a = __builtin_nontemporal_load(p + 16);
                f4 x1b = __builtin_nontemporal_load(p + 17);
                f4 x2a = __builtin_nontemporal_load(p + 32);
                f4 x2b = __builtin_nontemporal_load(p + 33);
                f4 aA = {accA.x, accA.y, accA.z, accA.w};
                f4 aB = {accB.x, accB.y, accB.z, accB.w};
                f4* dstn = reinterpret_cast<f4*>(dst);
                __builtin_nontemporal_store(aA, dstn + 0);
                __builtin_nontemporal_store(aB, dstn + 1);
                f4 ma = (x0a + x1a + x2a + aA) * 0.25f;
                f4 mb = (x0b + x1b + x2b + aB) * 0.25f;
                if (n < NUSERS) {
                    f4* ou = reinterpret_cast<f4*>(out_users + (size_t)n * 64 + lane * 8);
                    __builtin_nontemporal_store(ma, ou + 0);
                    __builtin_nontemporal_store(mb, ou + 1);
                }
                if (n >= NITEMS) {
                    f4* oi = reinterpret_cast<f4*>(out_items + (size_t)(n - NITEMS) * 64 + lane * 8);
                    __builtin_nontemporal_store(ma, oi + 0);
                    __builtin_nontemporal_store(mb, oi + 1);
                }
            }
        }
        if (L < 3) grid.sync();
    }
}

extern "C" void kernel_launch(void* const* d_in, const int* in_sizes, int n_in,
                              void* d_out, int out_size, void* d_ws, size_t ws_size,
                              hipStream_t stream) {
    const float* user  = (const float*)d_in[0];
    const float* item  = (const float*)d_in[1];
    const int*   edges = (const int*)d_in[2];
    const int*   row = edges;            // edge_index[0]
    const int*   col = edges + NE;       // edge_index[1]

    float* out       = (float*)d_out;
    float* out_users = out;
    float* out_items = out + (size_t)NUSERS * 64;
    float* all_emb   = out + (size_t)NUSERS * 64 * 2;   // [700000][4][64]

    // workspace carve (~215 MB)
    char* ws = (char*)d_ws;
    uint4* xb0   = (uint4*)ws;                        ws += (size_t)NNODES * 128;  // bf16 [N][64]
    uint4* xb1   = (uint4*)ws;                        ws += (size_t)NNODES * 128;
    int*   sr    = (int*)ws;                          ws += (size_t)NE * 4;
    int*   deg   = (int*)ws;                          ws += (size_t)NNODES * 4;
    int*   offs  = (int*)ws;                          ws += (size_t)(NNODES + 1) * 4;
    int*   cursor= (int*)ws;                          ws += (size_t)NNODES * 4;
    int*   bsums = (int*)ws;                          ws += (size_t)SCAN_B * 4;
    float* dinv  = (float*)ws;                        ws += (size_t)NNODES * 4;
    int*   perm  = (int*)ws;                          ws += (size_t)NNODES * 4;
    int*   dcnt  = (int*)ws;                          ws += 256 * 4;
    int*   dcur  = (int*)ws;                          ws += 256 * 4;

    const int B = 256;

    (void)hipMemsetAsync(deg, 0, (size_t)NNODES * sizeof(int), stream);
    (void)hipMemsetAsync(dcnt, 0, 256 * sizeof(int), stream);
    k_hist    <<<(NE + B - 1) / B, B, 0, stream>>>(col, deg);
    k_scan1   <<<NSB, SCAN_B, 0, stream>>>(deg, offs, bsums);
    k_scan2   <<<1, SCAN_B, 0, stream>>>(bsums);
    k_scan3   <<<(NNODES + B - 1) / B, B, 0, stream>>>(offs, bsums, cursor, deg, dinv);
    k_dcount  <<<1024, 256, 0, stream>>>(deg, dcnt);
    k_dscan   <<<1, 256, 0, stream>>>(dcnt, dcur);
    k_dscatter<<<(NNODES + 255) / 256, 256, 0, stream>>>(deg, dcur, perm);
    k_scatter <<<(NE + B - 1) / B, B, 0, stream>>>(row, col, cursor, sr);

    // cooperative fused main phase: __launch_bounds__(256,4) guarantees
    // >=16 waves/CU -> 4 blocks/CU co-resident -> grid of 1024 is safe.
    const float4* user4 = (const float4*)user;
    const float4* item4 = (const float4*)item;
    float4* all4 = (float4*)all_emb;
    void* args[] = {(void*)&user4, (void*)&item4, (void*)&perm, (void*)&offs,
                    (void*)&sr, (void*)&dinv, (void*)&xb0, (void*)&xb1,
                    (void*)&all4, (void*)&out_users, (void*)&out_items};
    (void)hipLaunchCooperativeKernel((void*)k_fused, dim3(1024), dim3(256),
                                     args, 0, stream);
}

// Round 9
// 1237.432 us; speedup vs baseline: 1.4081x; 1.4081x over previous
//
#include <hip/hip_runtime.h>

// LightGCN 3-layer propagation — R9: separate kernels (R7 structure) +
// prescaled bf16 mirror + 4B edge records (from R8) + nt stores for ALL fp32
// layer writes (protect L3-resident mirror from streaming evictions).
//
// R8 post-mortem: coop fusion at 1024 blocks = 48% occupancy cost 1.75x on
// the main phase (669 -> 1166us). FETCH showed ~700MB gather L3-misses caused
// by regular fp32 stores flushing the 89.6MB bf16 mirror. Revert fusion;
// evict-first the write-only fp32 stack.

static constexpr int NUSERS = 500000;
static constexpr int NITEMS = 200000;
static constexpr int NNODES = 700000;   // NUSERS + NITEMS
static constexpr int NE     = 5000000;
static constexpr int SCAN_B = 1024;
static constexpr int NSB    = (NNODES + SCAN_B - 1) / SCAN_B;   // 684 scan blocks

typedef float f4 __attribute__((ext_vector_type(4)));   // native vec for nt ops

// round-to-nearest-even fp32 -> bf16 (as uint16 in low bits)
__device__ inline unsigned bf16rne(float f) {
    unsigned u = __float_as_uint(f);
    return (u + 0x7FFFu + ((u >> 16) & 1u)) >> 16;
}
__device__ inline unsigned packbf(float lo, float hi) {
    return bf16rne(lo) | (bf16rne(hi) << 16);
}
__device__ inline void acc8(float4& A, float4& B, uint4 q) {
    A.x += __uint_as_float(q.x << 16); A.y += __uint_as_float(q.x & 0xFFFF0000u);
    A.z += __uint_as_float(q.y << 16); A.w += __uint_as_float(q.y & 0xFFFF0000u);
    B.x += __uint_as_float(q.z << 16); B.y += __uint_as_float(q.z & 0xFFFF0000u);
    B.z += __uint_as_float(q.w << 16); B.w += __uint_as_float(q.w & 0xFFFF0000u);
}

// ===================== sort pipeline ====================
__global__ void k_hist(const int* __restrict__ col, int* __restrict__ deg) {
    int e = blockIdx.x * blockDim.x + threadIdx.x;
    if (e < NE) atomicAdd(&deg[col[e]], 1);
}

__global__ void k_scan1(const int* __restrict__ deg, int* __restrict__ offs,
                        int* __restrict__ bsums) {
    __shared__ int s[SCAN_B];
    int t = threadIdx.x;
    int i = blockIdx.x * SCAN_B + t;
    int v = (i < NNODES) ? deg[i] : 0;
    s[t] = v;
    __syncthreads();
    for (int off = 1; off < SCAN_B; off <<= 1) {
        int add = (t >= off) ? s[t - off] : 0;
        __syncthreads();
        s[t] += add;
        __syncthreads();
    }
    if (i < NNODES) offs[i] = s[t] - v;
    if (t == SCAN_B - 1) bsums[blockIdx.x] = s[t];
}

__global__ void k_scan2(int* __restrict__ bsums) {
    __shared__ int s[SCAN_B];
    int t = threadIdx.x;
    int v = (t < NSB) ? bsums[t] : 0;
    s[t] = v;
    __syncthreads();
    for (int off = 1; off < SCAN_B; off <<= 1) {
        int add = (t >= off) ? s[t - off] : 0;
        __syncthreads();
        s[t] += add;
        __syncthreads();
    }
    if (t < NSB) bsums[t] = s[t] - v;
}

__global__ void k_scan3(int* __restrict__ offs, const int* __restrict__ bsums,
                        int* __restrict__ cursor, const int* __restrict__ deg,
                        float* __restrict__ dinv) {
    int i = blockIdx.x * blockDim.x + threadIdx.x;
    if (i < NNODES) {
        int o = offs[i] + bsums[i >> 10];
        offs[i]   = o;
        cursor[i] = o;
        int d = deg[i];
        dinv[i] = (d > 0) ? rsqrtf((float)d) : 0.0f;
    }
    if (i == 0) offs[NNODES] = NE;
}

__global__ void k_dcount(const int* __restrict__ deg, int* __restrict__ dcnt) {
    __shared__ int h[256];
    int t = threadIdx.x;
    h[t] = 0;
    __syncthreads();
    for (int n = blockIdx.x * blockDim.x + t; n < NNODES; n += gridDim.x * blockDim.x)
        atomicAdd(&h[min(deg[n], 255)], 1);
    __syncthreads();
    if (h[t]) atomicAdd(&dcnt[t], h[t]);
}

__global__ void k_dscan(const int* __restrict__ dcnt, int* __restrict__ dcur) {
    __shared__ int s[256];
    int t = threadIdx.x;
    int v = dcnt[t];
    s[t] = v;
    __syncthreads();
    for (int off = 1; off < 256; off <<= 1) {
        int add = (t >= off) ? s[t - off] : 0;
        __syncthreads();
        s[t] += add;
        __syncthreads();
    }
    dcur[t] = s[t] - v;
}

__global__ void k_dscatter(const int* __restrict__ deg, int* __restrict__ dcur,
                           int* __restrict__ perm) {
    __shared__ int lcnt[256];
    __shared__ int lbase[256];
    int t = threadIdx.x;
    lcnt[t] = 0;
    __syncthreads();
    int n = blockIdx.x * 256 + t;
    int bucket = 0, lrank = 0;
    if (n < NNODES) {
        bucket = min(deg[n], 255);
        lrank = atomicAdd(&lcnt[bucket], 1);
    }
    __syncthreads();
    if (lcnt[t]) lbase[t] = atomicAdd(&dcur[t], lcnt[t]);
    __syncthreads();
    if (n < NNODES) perm[lbase[bucket] + lrank] = n;
}

// edge scatter: record is just the source id (4 B)
__global__ void k_scatter(const int* __restrict__ row, const int* __restrict__ col,
                          int* __restrict__ cursor, int* __restrict__ sr) {
    int e = blockIdx.x * blockDim.x + threadIdx.x;
    if (e >= NE) return;
    int r = row[e], c = col[e];
    int pos = atomicAdd(&cursor[c], 1);
    sr[pos] = r;
}

// --- init: layer-0 fp32 (nt) + prescaled bf16 mirror -------------------------
__global__ void k_init(const float4* __restrict__ user, const float4* __restrict__ item,
                       float4* __restrict__ all_emb, const float* __restrict__ dinv,
                       uint4* __restrict__ xb0) {
    int tid = blockIdx.x * blockDim.x + threadIdx.x;
    if (tid >= NNODES * 8) return;
    int n    = tid >> 3;
    int lane = tid & 7;
    const float4* s = ((n < NUSERS) ? user + (size_t)n * 16
                                    : item + (size_t)(n - NUSERS) * 16) + lane * 2;
    float4 a = s[0], b = s[1];
    f4* dst = reinterpret_cast<f4*>(all_emb + (size_t)n * 64 + lane * 2);
    f4 av = {a.x, a.y, a.z, a.w};
    f4 bv = {b.x, b.y, b.z, b.w};
    __builtin_nontemporal_store(av, dst + 0);
    __builtin_nontemporal_store(bv, dst + 1);
    float dv = dinv[n];
    uint4 o;
    o.x = packbf(dv * a.x, dv * a.y); o.y = packbf(dv * a.z, dv * a.w);
    o.z = packbf(dv * b.x, dv * b.y); o.w = packbf(dv * b.z, dv * b.w);
    xb0[(size_t)n * 8 + lane] = o;
}

// --- propagate layer L: bf16 gather (prescaled), fp32 accumulate -------------
// 8 threads per node, 8 dims each. fp32 stack stores are ALL non-temporal.
template <int L, bool FUSE_OUT>
__global__ void k_prop(const int* __restrict__ perm, const int* __restrict__ offs,
                       const int* __restrict__ sr, const float* __restrict__ dinv,
                       const uint4* __restrict__ xbp,   // bf16 src mirror (layer L-1)
                       uint4* __restrict__ xbc,         // bf16 dst mirror (layer L)
                       float4* __restrict__ all_emb,
                       float* __restrict__ out_users, float* __restrict__ out_items) {
    int tid = blockIdx.x * blockDim.x + threadIdx.x;
    if (tid >= NNODES * 8) return;
    int g    = tid >> 3;
    int lane = tid & 7;
    int n = perm[g];
    int b = offs[n], e = offs[n + 1];
    float4 accA = make_float4(0.f, 0.f, 0.f, 0.f);
    float4 accB = make_float4(0.f, 0.f, 0.f, 0.f);
    const uint4* src = xbp + lane;

    int k = b;
    for (; k + 4 <= e; k += 4) {
        int r0 = sr[k + 0], r1 = sr[k + 1], r2 = sr[k + 2], r3 = sr[k + 3];
        uint4 q0 = src[(size_t)r0 * 8];
        uint4 q1 = src[(size_t)r1 * 8];
        uint4 q2 = src[(size_t)r2 * 8];
        uint4 q3 = src[(size_t)r3 * 8];
        acc8(accA, accB, q0); acc8(accA, accB, q1);
        acc8(accA, accB, q2); acc8(accA, accB, q3);
    }
    for (; k < e; ++k) {
        uint4 q = src[(size_t)sr[k] * 8];
        acc8(accA, accB, q);
    }
    float dv = dinv[n];
    accA.x *= dv; accA.y *= dv; accA.z *= dv; accA.w *= dv;
    accB.x *= dv; accB.y *= dv; accB.z *= dv; accB.w *= dv;

    f4 aA = {accA.x, accA.y, accA.z, accA.w};
    f4 aB = {accB.x, accB.y, accB.z, accB.w};
    f4* dstn = reinterpret_cast<f4*>(all_emb + (size_t)n * 64 + L * 16 + lane * 2);
    __builtin_nontemporal_store(aA, dstn + 0);
    __builtin_nontemporal_store(aB, dstn + 1);

    if constexpr (!FUSE_OUT) {
        uint4 o;
        o.x = packbf(dv * accA.x, dv * accA.y);
        o.y = packbf(dv * accA.z, dv * accA.w);
        o.z = packbf(dv * accB.x, dv * accB.y);
        o.w = packbf(dv * accB.z, dv * accB.w);
        xbc[(size_t)n * 8 + lane] = o;
    } else {
        const f4* p = reinterpret_cast<const f4*>(all_emb + (size_t)n * 64 + lane * 2);
        f4 x0a = __builtin_nontemporal_load(p + 0);
        f4 x0b = __builtin_nontemporal_load(p + 1);
        f4 x1a = __builtin_nontemporal_load(p + 16);
        f4 x1b = __builtin_nontemporal_load(p + 17);
        f4 x2a = __builtin_nontemporal_load(p + 32);
        f4 x2b = __builtin_nontemporal_load(p + 33);
        f4 ma = (x0a + x1a + x2a + aA) * 0.25f;
        f4 mb = (x0b + x1b + x2b + aB) * 0.25f;
        if (n < NUSERS) {
            f4* ou = reinterpret_cast<f4*>(out_users + (size_t)n * 64 + lane * 8);
            __builtin_nontemporal_store(ma, ou + 0);
            __builtin_nontemporal_store(mb, ou + 1);
        }
        if (n >= NITEMS) {
            f4* oi = reinterpret_cast<f4*>(out_items + (size_t)(n - NITEMS) * 64 + lane * 8);
            __builtin_nontemporal_store(ma, oi + 0);
            __builtin_nontemporal_store(mb, oi + 1);
        }
    }
}

extern "C" void kernel_launch(void* const* d_in, const int* in_sizes, int n_in,
                              void* d_out, int out_size, void* d_ws, size_t ws_size,
                              hipStream_t stream) {
    const float* user  = (const float*)d_in[0];
    const float* item  = (const float*)d_in[1];
    const int*   edges = (const int*)d_in[2];
    const int*   row = edges;            // edge_index[0]
    const int*   col = edges + NE;       // edge_index[1]

    float* out       = (float*)d_out;
    float* out_users = out;
    float* out_items = out + (size_t)NUSERS * 64;
    float* all_emb   = out + (size_t)NUSERS * 64 * 2;   // [700000][4][64]

    // workspace carve (~215 MB)
    char* ws = (char*)d_ws;
    uint4* xb0   = (uint4*)ws;                        ws += (size_t)NNODES * 128;  // bf16 [N][64]
    uint4* xb1   = (uint4*)ws;                        ws += (size_t)NNODES * 128;
    int*   sr    = (int*)ws;                          ws += (size_t)NE * 4;
    int*   deg   = (int*)ws;                          ws += (size_t)NNODES * 4;
    int*   offs  = (int*)ws;                          ws += (size_t)(NNODES + 1) * 4;
    int*   cursor= (int*)ws;                          ws += (size_t)NNODES * 4;
    int*   bsums = (int*)ws;                          ws += (size_t)SCAN_B * 4;
    float* dinv  = (float*)ws;                        ws += (size_t)NNODES * 4;
    int*   perm  = (int*)ws;                          ws += (size_t)NNODES * 4;
    int*   dcnt  = (int*)ws;                          ws += 256 * 4;
    int*   dcur  = (int*)ws;                          ws += 256 * 4;

    const int B = 256;
    const int prop_grid = (NNODES * 8 + B - 1) / B;

    (void)hipMemsetAsync(deg, 0, (size_t)NNODES * sizeof(int), stream);
    (void)hipMemsetAsync(dcnt, 0, 256 * sizeof(int), stream);
    k_hist    <<<(NE + B - 1) / B, B, 0, stream>>>(col, deg);
    k_scan1   <<<NSB, SCAN_B, 0, stream>>>(deg, offs, bsums);
    k_scan2   <<<1, SCAN_B, 0, stream>>>(bsums);
    k_scan3   <<<(NNODES + B - 1) / B, B, 0, stream>>>(offs, bsums, cursor, deg, dinv);
    k_dcount  <<<1024, 256, 0, stream>>>(deg, dcnt);
    k_dscan   <<<1, 256, 0, stream>>>(dcnt, dcur);
    k_dscatter<<<(NNODES + 255) / 256, 256, 0, stream>>>(deg, dcur, perm);
    k_scatter <<<(NE + B - 1) / B, B, 0, stream>>>(row, col, cursor, sr);
    k_init    <<<prop_grid, B, 0, stream>>>(
        (const float4*)user, (const float4*)item, (float4*)all_emb, dinv, xb0);

    k_prop<1, false><<<prop_grid, B, 0, stream>>>(perm, offs, sr, dinv, xb0, xb1,
                                                  (float4*)all_emb, nullptr, nullptr);
    k_prop<2, false><<<prop_grid, B, 0, stream>>>(perm, offs, sr, dinv, xb1, xb0,
                                                  (float4*)all_emb, nullptr, nullptr);
    k_prop<3, true> <<<prop_grid, B, 0, stream>>>(perm, offs, sr, dinv, xb0, nullptr,
                                                  (float4*)all_emb, out_users, out_items);
}

// Round 10
// 926.188 us; speedup vs baseline: 1.8813x; 1.3360x over previous
//
#include <hip/hip_runtime.h>

// LightGCN 3-layer propagation — R10: bucket-partitioned counting sort.
//
// R9 post-mortem: main phase ~670us, sort pipeline ~570us. Sort waste: 5M
// contended global atomics (hist) + 5M cursor atomics + 5M random 4B writes
// (scatter, ~320MB line-RMW). R10 replaces hist/scan1-3/scatter with:
//   k_bcount: LDS hist of 684 col-buckets (bucket = col>>10)
//   k_bscan:  scan bucket sizes -> bbase (= edge offsets of node ranges)
//   k_bpart:  partition edges into buckets, packed (c_local<<20)|r, LDS ranks,
//             ~684 global atomics/block, run-granular writes
//   k_bsort:  per-bucket LDS counting sort -> deg/dinv/offs free + coalesced-
//             window sr placement (L2-local)
// Main phase (init + 3 props, bf16 prescaled mirror, nt stores) unchanged.

static constexpr int NUSERS = 500000;
static constexpr int NITEMS = 200000;
static constexpr int NNODES = 700000;   // NUSERS + NITEMS
static constexpr int NE     = 5000000;
static constexpr int NB     = (NNODES + 1023) / 1024;   // 684 buckets
static constexpr int CH     = 4096;                     // edges per k_bpart block

typedef float f4 __attribute__((ext_vector_type(4)));   // native vec for nt ops

// round-to-nearest-even fp32 -> bf16 (as uint16 in low bits)
__device__ inline unsigned bf16rne(float f) {
    unsigned u = __float_as_uint(f);
    return (u + 0x7FFFu + ((u >> 16) & 1u)) >> 16;
}
__device__ inline unsigned packbf(float lo, float hi) {
    return bf16rne(lo) | (bf16rne(hi) << 16);
}
__device__ inline void acc8(float4& A, float4& B, uint4 q) {
    A.x += __uint_as_float(q.x << 16); A.y += __uint_as_float(q.x & 0xFFFF0000u);
    A.z += __uint_as_float(q.y << 16); A.w += __uint_as_float(q.y & 0xFFFF0000u);
    B.x += __uint_as_float(q.z << 16); B.y += __uint_as_float(q.z & 0xFFFF0000u);
    B.z += __uint_as_float(q.w << 16); B.w += __uint_as_float(q.w & 0xFFFF0000u);
}

// ===================== bucket sort pipeline =====================

// --- bucket histogram (LDS-privatized) ---------------------------------------
__global__ void k_bcount(const int* __restrict__ col, int* __restrict__ bcnt) {
    __shared__ int h[NB];
    int t = threadIdx.x;
    for (int i = t; i < NB; i += 256) h[i] = 0;
    __syncthreads();
    for (int e = blockIdx.x * blockDim.x + t; e < NE; e += gridDim.x * blockDim.x)
        atomicAdd(&h[col[e] >> 10], 1);
    __syncthreads();
    for (int i = t; i < NB; i += 256)
        if (h[i]) atomicAdd(&bcnt[i], h[i]);
}

// --- scan bucket counts -> bbase[NB+1], bcur copy; offs[NNODES]=NE -----------
__global__ void k_bscan(const int* __restrict__ bcnt, int* __restrict__ bbase,
                        int* __restrict__ bcur, int* __restrict__ offs) {
    __shared__ int s[1024];
    int t = threadIdx.x;
    int v = (t < NB) ? bcnt[t] : 0;
    s[t] = v;
    __syncthreads();
    for (int off = 1; off < 1024; off <<= 1) {
        int add = (t >= off) ? s[t - off] : 0;
        __syncthreads();
        s[t] += add;
        __syncthreads();
    }
    int excl = s[t] - v;
    if (t < NB) { bbase[t] = excl; bcur[t] = excl; }
    if (t == NB - 1) bbase[NB] = excl + v;       // = NE
    if (t == 0) offs[NNODES] = NE;
}

// --- partition edges into buckets (packed (c_local<<20)|r) -------------------
__global__ void k_bpart(const int* __restrict__ row, const int* __restrict__ col,
                        int* __restrict__ bcur, unsigned* __restrict__ pairs) {
    __shared__ unsigned pe[CH];      // packed (c_local<<20)|r
    __shared__ unsigned short pb[CH];// bucket id
    __shared__ int lh[NB];
    __shared__ int lbase[NB];
    int t = threadIdx.x;
    for (int i = t; i < NB; i += 256) lh[i] = 0;
    __syncthreads();
    int base = blockIdx.x * CH;
    int cnt = min(CH, NE - base);
    for (int i = t; i < cnt; i += 256) {
        int c = col[base + i], r = row[base + i];
        int b = c >> 10;
        pe[i] = ((unsigned)(c & 1023) << 20) | (unsigned)r;
        pb[i] = (unsigned short)b;
        atomicAdd(&lh[b], 1);
    }
    __syncthreads();
    for (int b = t; b < NB; b += 256) {
        int v = lh[b];
        if (v) lbase[b] = atomicAdd(&bcur[b], v);
        lh[b] = 0;                                // re-zero for rank pass
    }
    __syncthreads();
    for (int i = t; i < cnt; i += 256) {
        int b = pb[i];
        int pos = lbase[b] + atomicAdd(&lh[b], 1);
        pairs[pos] = pe[i];
    }
}

// --- per-bucket counting sort: deg/dinv/offs + sr placement ------------------
__global__ void k_bsort(const unsigned* __restrict__ pairs, const int* __restrict__ bbase,
                        int* __restrict__ sr, int* __restrict__ deg,
                        float* __restrict__ dinv, int* __restrict__ offs) {
    __shared__ int cnt[1024];
    __shared__ int cur[1024];
    __shared__ int part[256];
    int b = blockIdx.x;
    int t = threadIdx.x;
    int lo = bbase[b], hi = bbase[b + 1];
    int nbase = b << 10;
    for (int i = t; i < 1024; i += 256) cnt[i] = 0;
    __syncthreads();
    for (int k = lo + t; k < hi; k += 256)
        atomicAdd(&cnt[pairs[k] >> 20], 1);
    __syncthreads();
    // exclusive scan of cnt[1024]: 4 per thread + HS on 256 partials
    int s0 = cnt[t * 4], s1 = cnt[t * 4 + 1], s2 = cnt[t * 4 + 2], s3 = cnt[t * 4 + 3];
    int tot = s0 + s1 + s2 + s3;
    part[t] = tot;
    __syncthreads();
    for (int off = 1; off < 256; off <<= 1) {
        int add = (t >= off) ? part[t - off] : 0;
        __syncthreads();
        part[t] += add;
        __syncthreads();
    }
    int pbase = part[t] - tot;                    // exclusive
    int e0 = pbase, e1 = pbase + s0, e2 = e1 + s1, e3 = e2 + s2;
    cur[t * 4] = e0; cur[t * 4 + 1] = e1; cur[t * 4 + 2] = e2; cur[t * 4 + 3] = e3;
    int n0 = nbase + t * 4;
    if (n0 + 0 < NNODES) { deg[n0+0]=s0; dinv[n0+0]= s0 ? rsqrtf((float)s0):0.f; offs[n0+0]=lo+e0; }
    if (n0 + 1 < NNODES) { deg[n0+1]=s1; dinv[n0+1]= s1 ? rsqrtf((float)s1):0.f; offs[n0+1]=lo+e1; }
    if (n0 + 2 < NNODES) { deg[n0+2]=s2; dinv[n0+2]= s2 ? rsqrtf((float)s2):0.f; offs[n0+2]=lo+e2; }
    if (n0 + 3 < NNODES) { deg[n0+3]=s3; dinv[n0+3]= s3 ? rsqrtf((float)s3):0.f; offs[n0+3]=lo+e3; }
    __syncthreads();
    for (int k = lo + t; k < hi; k += 256) {
        unsigned u = pairs[k];
        int pos = lo + atomicAdd(&cur[u >> 20], 1);
        sr[pos] = (int)(u & 0xFFFFFu);
    }
}

// ===================== degree-sorted node permutation =====================
__global__ void k_dcount(const int* __restrict__ deg, int* __restrict__ dcnt) {
    __shared__ int h[256];
    int t = threadIdx.x;
    h[t] = 0;
    __syncthreads();
    for (int n = blockIdx.x * blockDim.x + t; n < NNODES; n += gridDim.x * blockDim.x)
        atomicAdd(&h[min(deg[n], 255)], 1);
    __syncthreads();
    if (h[t]) atomicAdd(&dcnt[t], h[t]);
}

__global__ void k_dscan(const int* __restrict__ dcnt, int* __restrict__ dcur) {
    __shared__ int s[256];
    int t = threadIdx.x;
    int v = dcnt[t];
    s[t] = v;
    __syncthreads();
    for (int off = 1; off < 256; off <<= 1) {
        int add = (t >= off) ? s[t - off] : 0;
        __syncthreads();
        s[t] += add;
        __syncthreads();
    }
    dcur[t] = s[t] - v;
}

__global__ void k_dscatter(const int* __restrict__ deg, int* __restrict__ dcur,
                           int* __restrict__ perm) {
    __shared__ int lcnt[256];
    __shared__ int lbase[256];
    int t = threadIdx.x;
    lcnt[t] = 0;
    __syncthreads();
    int n = blockIdx.x * 256 + t;
    int bucket = 0, lrank = 0;
    if (n < NNODES) {
        bucket = min(deg[n], 255);
        lrank = atomicAdd(&lcnt[bucket], 1);
    }
    __syncthreads();
    if (lcnt[t]) lbase[t] = atomicAdd(&dcur[t], lcnt[t]);
    __syncthreads();
    if (n < NNODES) perm[lbase[bucket] + lrank] = n;
}

// ===================== main phase =====================

// --- init: layer-0 fp32 (nt) + prescaled bf16 mirror -------------------------
__global__ void k_init(const float4* __restrict__ user, const float4* __restrict__ item,
                       float4* __restrict__ all_emb, const float* __restrict__ dinv,
                       uint4* __restrict__ xb0) {
    int tid = blockIdx.x * blockDim.x + threadIdx.x;
    if (tid >= NNODES * 8) return;
    int n    = tid >> 3;
    int lane = tid & 7;
    const float4* s = ((n < NUSERS) ? user + (size_t)n * 16
                                    : item + (size_t)(n - NUSERS) * 16) + lane * 2;
    float4 a = s[0], b = s[1];
    f4* dst = reinterpret_cast<f4*>(all_emb + (size_t)n * 64 + lane * 2);
    f4 av = {a.x, a.y, a.z, a.w};
    f4 bv = {b.x, b.y, b.z, b.w};
    __builtin_nontemporal_store(av, dst + 0);
    __builtin_nontemporal_store(bv, dst + 1);
    float dv = dinv[n];
    uint4 o;
    o.x = packbf(dv * a.x, dv * a.y); o.y = packbf(dv * a.z, dv * a.w);
    o.z = packbf(dv * b.x, dv * b.y); o.w = packbf(dv * b.z, dv * b.w);
    xb0[(size_t)n * 8 + lane] = o;
}

// --- propagate layer L: bf16 gather (prescaled), fp32 accumulate -------------
template <int L, bool FUSE_OUT>
__global__ void k_prop(const int* __restrict__ perm, const int* __restrict__ offs,
                       const int* __restrict__ sr, const float* __restrict__ dinv,
                       const uint4* __restrict__ xbp,
                       uint4* __restrict__ xbc,
                       float4* __restrict__ all_emb,
                       float* __restrict__ out_users, float* __restrict__ out_items) {
    int tid = blockIdx.x * blockDim.x + threadIdx.x;
    if (tid >= NNODES * 8) return;
    int g    = tid >> 3;
    int lane = tid & 7;
    int n = perm[g];
    int b = offs[n], e = offs[n + 1];
    float4 accA = make_float4(0.f, 0.f, 0.f, 0.f);
    float4 accB = make_float4(0.f, 0.f, 0.f, 0.f);
    const uint4* src = xbp + lane;

    int k = b;
    for (; k + 4 <= e; k += 4) {
        int r0 = sr[k + 0], r1 = sr[k + 1], r2 = sr[k + 2], r3 = sr[k + 3];
        uint4 q0 = src[(size_t)r0 * 8];
        uint4 q1 = src[(size_t)r1 * 8];
        uint4 q2 = src[(size_t)r2 * 8];
        uint4 q3 = src[(size_t)r3 * 8];
        acc8(accA, accB, q0); acc8(accA, accB, q1);
        acc8(accA, accB, q2); acc8(accA, accB, q3);
    }
    for (; k < e; ++k) {
        uint4 q = src[(size_t)sr[k] * 8];
        acc8(accA, accB, q);
    }
    float dv = dinv[n];
    accA.x *= dv; accA.y *= dv; accA.z *= dv; accA.w *= dv;
    accB.x *= dv; accB.y *= dv; accB.z *= dv; accB.w *= dv;

    f4 aA = {accA.x, accA.y, accA.z, accA.w};
    f4 aB = {accB.x, accB.y, accB.z, accB.w};
    f4* dstn = reinterpret_cast<f4*>(all_emb + (size_t)n * 64 + L * 16 + lane * 2);
    __builtin_nontemporal_store(aA, dstn + 0);
    __builtin_nontemporal_store(aB, dstn + 1);

    if constexpr (!FUSE_OUT) {
        uint4 o;
        o.x = packbf(dv * accA.x, dv * accA.y);
        o.y = packbf(dv * accA.z, dv * accA.w);
        o.z = packbf(dv * accB.x, dv * accB.y);
        o.w = packbf(dv * accB.z, dv * accB.w);
        xbc[(size_t)n * 8 + lane] = o;
    } else {
        const f4* p = reinterpret_cast<const f4*>(all_emb + (size_t)n * 64 + lane * 2);
        f4 x0a = __builtin_nontemporal_load(p + 0);
        f4 x0b = __builtin_nontemporal_load(p + 1);
        f4 x1a = __builtin_nontemporal_load(p + 16);
        f4 x1b = __builtin_nontemporal_load(p + 17);
        f4 x2a = __builtin_nontemporal_load(p + 32);
        f4 x2b = __builtin_nontemporal_load(p + 33);
        f4 ma = (x0a + x1a + x2a + aA) * 0.25f;
        f4 mb = (x0b + x1b + x2b + aB) * 0.25f;
        if (n < NUSERS) {
            f4* ou = reinterpret_cast<f4*>(out_users + (size_t)n * 64 + lane * 8);
            __builtin_nontemporal_store(ma, ou + 0);
            __builtin_nontemporal_store(mb, ou + 1);
        }
        if (n >= NITEMS) {
            f4* oi = reinterpret_cast<f4*>(out_items + (size_t)(n - NITEMS) * 64 + lane * 8);
            __builtin_nontemporal_store(ma, oi + 0);
            __builtin_nontemporal_store(mb, oi + 1);
        }
    }
}

extern "C" void kernel_launch(void* const* d_in, const int* in_sizes, int n_in,
                              void* d_out, int out_size, void* d_ws, size_t ws_size,
                              hipStream_t stream) {
    const float* user  = (const float*)d_in[0];
    const float* item  = (const float*)d_in[1];
    const int*   edges = (const int*)d_in[2];
    const int*   row = edges;            // edge_index[0]
    const int*   col = edges + NE;       // edge_index[1]

    float* out       = (float*)d_out;
    float* out_users = out;
    float* out_items = out + (size_t)NUSERS * 64;
    float* all_emb   = out + (size_t)NUSERS * 64 * 2;   // [700000][4][64]

    // workspace carve (~231 MB)
    char* ws = (char*)d_ws;
    uint4*    xb0   = (uint4*)ws;                     ws += (size_t)NNODES * 128;
    uint4*    xb1   = (uint4*)ws;                     ws += (size_t)NNODES * 128;
    unsigned* pairs = (unsigned*)ws;                  ws += (size_t)NE * 4;
    int*      sr    = (int*)ws;                       ws += (size_t)NE * 4;
    int*      deg   = (int*)ws;                       ws += (size_t)NNODES * 4;
    int*      offs  = (int*)ws;                       ws += (size_t)(NNODES + 1) * 4;
    float*    dinv  = (float*)ws;                     ws += (size_t)NNODES * 4;
    int*      perm  = (int*)ws;                       ws += (size_t)NNODES * 4;
    int*      bcnt  = (int*)ws;                       ws += (size_t)NB * 4;
    int*      bbase = (int*)ws;                       ws += (size_t)(NB + 1) * 4;
    int*      bcur  = (int*)ws;                       ws += (size_t)NB * 4;
    int*      dcnt  = (int*)ws;                       ws += 256 * 4;
    int*      dcur  = (int*)ws;                       ws += 256 * 4;

    const int B = 256;
    const int prop_grid = (NNODES * 8 + B - 1) / B;

    (void)hipMemsetAsync(bcnt, 0, (size_t)NB * sizeof(int), stream);
    (void)hipMemsetAsync(dcnt, 0, 256 * sizeof(int), stream);
    k_bcount  <<<1024, 256, 0, stream>>>(col, bcnt);
    k_bscan   <<<1, 1024, 0, stream>>>(bcnt, bbase, bcur, offs);
    k_bpart   <<<(NE + CH - 1) / CH, 256, 0, stream>>>(row, col, bcur, pairs);
    k_bsort   <<<NB, 256, 0, stream>>>(pairs, bbase, sr, deg, dinv, offs);
    k_dcount  <<<1024, 256, 0, stream>>>(deg, dcnt);
    k_dscan   <<<1, 256, 0, stream>>>(dcnt, dcur);
    k_dscatter<<<(NNODES + 255) / 256, 256, 0, stream>>>(deg, dcur, perm);
    k_init    <<<prop_grid, B, 0, stream>>>(
        (const float4*)user, (const float4*)item, (float4*)all_emb, dinv, xb0);

    k_prop<1, false><<<prop_grid, B, 0, stream>>>(perm, offs, sr, dinv, xb0, xb1,
                                                  (float4*)all_emb, nullptr, nullptr);
    k_prop<2, false><<<prop_grid, B, 0, stream>>>(perm, offs, sr, dinv, xb1, xb0,
                                                  (float4*)all_emb, nullptr, nullptr);
    k_prop<3, true> <<<prop_grid, B, 0, stream>>>(perm, offs, sr, dinv, xb0, nullptr,
                                                  (float4*)all_emb, out_users, out_items);
}

// Round 11
// 782.691 us; speedup vs baseline: 2.2262x; 1.1833x over previous
//
#include <hip/hip_runtime.h>

// LightGCN 3-layer propagation — R11: R10 minus perm machinery, offs2 int2.
//
// R10 post-mortem: main phase (~670us) is within ~5% of combined
// L3-gather(6TB/s)+HBM-write(6.3TB/s) roofline. Slack is sort/aux:
//  - drop degree-perm (3 kernels + perm[] indirection) — props are memory-
//    bound, divergence waste invisible; perm was never isolated as a win.
//  - k_bsort emits offs2[n]=(begin,end) -> one 8B load per prop thread,
//    deletes deg/offs arrays.

static constexpr int NUSERS = 500000;
static constexpr int NITEMS = 200000;
static constexpr int NNODES = 700000;   // NUSERS + NITEMS
static constexpr int NE     = 5000000;
static constexpr int NB     = (NNODES + 1023) / 1024;   // 684 buckets
static constexpr int CH     = 4096;                     // edges per k_bpart block

typedef float f4 __attribute__((ext_vector_type(4)));   // native vec for nt ops

// round-to-nearest-even fp32 -> bf16 (as uint16 in low bits)
__device__ inline unsigned bf16rne(float f) {
    unsigned u = __float_as_uint(f);
    return (u + 0x7FFFu + ((u >> 16) & 1u)) >> 16;
}
__device__ inline unsigned packbf(float lo, float hi) {
    return bf16rne(lo) | (bf16rne(hi) << 16);
}
__device__ inline void acc8(float4& A, float4& B, uint4 q) {
    A.x += __uint_as_float(q.x << 16); A.y += __uint_as_float(q.x & 0xFFFF0000u);
    A.z += __uint_as_float(q.y << 16); A.w += __uint_as_float(q.y & 0xFFFF0000u);
    B.x += __uint_as_float(q.z << 16); B.y += __uint_as_float(q.z & 0xFFFF0000u);
    B.z += __uint_as_float(q.w << 16); B.w += __uint_as_float(q.w & 0xFFFF0000u);
}

// ===================== bucket sort pipeline =====================

// --- bucket histogram (LDS-privatized) ---------------------------------------
__global__ void k_bcount(const int* __restrict__ col, int* __restrict__ bcnt) {
    __shared__ int h[NB];
    int t = threadIdx.x;
    for (int i = t; i < NB; i += 256) h[i] = 0;
    __syncthreads();
    for (int e = blockIdx.x * blockDim.x + t; e < NE; e += gridDim.x * blockDim.x)
        atomicAdd(&h[col[e] >> 10], 1);
    __syncthreads();
    for (int i = t; i < NB; i += 256)
        if (h[i]) atomicAdd(&bcnt[i], h[i]);
}

// --- scan bucket counts -> bbase[NB+1], bcur copy ----------------------------
__global__ void k_bscan(const int* __restrict__ bcnt, int* __restrict__ bbase,
                        int* __restrict__ bcur) {
    __shared__ int s[1024];
    int t = threadIdx.x;
    int v = (t < NB) ? bcnt[t] : 0;
    s[t] = v;
    __syncthreads();
    for (int off = 1; off < 1024; off <<= 1) {
        int add = (t >= off) ? s[t - off] : 0;
        __syncthreads();
        s[t] += add;
        __syncthreads();
    }
    int excl = s[t] - v;
    if (t < NB) { bbase[t] = excl; bcur[t] = excl; }
    if (t == NB - 1) bbase[NB] = excl + v;       // = NE
}

// --- partition edges into buckets (packed (c_local<<20)|r) -------------------
__global__ void k_bpart(const int* __restrict__ row, const int* __restrict__ col,
                        int* __restrict__ bcur, unsigned* __restrict__ pairs) {
    __shared__ unsigned pe[CH];      // packed (c_local<<20)|r
    __shared__ unsigned short pb[CH];// bucket id
    __shared__ int lh[NB];
    __shared__ int lbase[NB];
    int t = threadIdx.x;
    for (int i = t; i < NB; i += 256) lh[i] = 0;
    __syncthreads();
    int base = blockIdx.x * CH;
    int cnt = min(CH, NE - base);
    for (int i = t; i < cnt; i += 256) {
        int c = col[base + i], r = row[base + i];
        int b = c >> 10;
        pe[i] = ((unsigned)(c & 1023) << 20) | (unsigned)r;
        pb[i] = (unsigned short)b;
        atomicAdd(&lh[b], 1);
    }
    __syncthreads();
    for (int b = t; b < NB; b += 256) {
        int v = lh[b];
        if (v) lbase[b] = atomicAdd(&bcur[b], v);
        lh[b] = 0;                                // re-zero for rank pass
    }
    __syncthreads();
    for (int i = t; i < cnt; i += 256) {
        int b = pb[i];
        int pos = lbase[b] + atomicAdd(&lh[b], 1);
        pairs[pos] = pe[i];
    }
}

// --- per-bucket counting sort: dinv/offs2 + sr placement ---------------------
__global__ void k_bsort(const unsigned* __restrict__ pairs, const int* __restrict__ bbase,
                        int* __restrict__ sr, float* __restrict__ dinv,
                        int2* __restrict__ offs2) {
    __shared__ int cnt[1024];
    __shared__ int cur[1024];
    __shared__ int part[256];
    int b = blockIdx.x;
    int t = threadIdx.x;
    int lo = bbase[b], hi = bbase[b + 1];
    int nbase = b << 10;
    for (int i = t; i < 1024; i += 256) cnt[i] = 0;
    __syncthreads();
    for (int k = lo + t; k < hi; k += 256)
        atomicAdd(&cnt[pairs[k] >> 20], 1);
    __syncthreads();
    // exclusive scan of cnt[1024]: 4 per thread + HS on 256 partials
    int s0 = cnt[t * 4], s1 = cnt[t * 4 + 1], s2 = cnt[t * 4 + 2], s3 = cnt[t * 4 + 3];
    int tot = s0 + s1 + s2 + s3;
    part[t] = tot;
    __syncthreads();
    for (int off = 1; off < 256; off <<= 1) {
        int add = (t >= off) ? part[t - off] : 0;
        __syncthreads();
        part[t] += add;
        __syncthreads();
    }
    int pbase = part[t] - tot;                    // exclusive
    int e0 = pbase, e1 = pbase + s0, e2 = e1 + s1, e3 = e2 + s2;
    cur[t * 4] = e0; cur[t * 4 + 1] = e1; cur[t * 4 + 2] = e2; cur[t * 4 + 3] = e3;
    int n0 = nbase + t * 4;
    if (n0 + 0 < NNODES) { dinv[n0+0] = s0 ? rsqrtf((float)s0) : 0.f;
                           offs2[n0+0] = make_int2(lo + e0, lo + e0 + s0); }
    if (n0 + 1 < NNODES) { dinv[n0+1] = s1 ? rsqrtf((float)s1) : 0.f;
                           offs2[n0+1] = make_int2(lo + e1, lo + e1 + s1); }
    if (n0 + 2 < NNODES) { dinv[n0+2] = s2 ? rsqrtf((float)s2) : 0.f;
                           offs2[n0+2] = make_int2(lo + e2, lo + e2 + s2); }
    if (n0 + 3 < NNODES) { dinv[n0+3] = s3 ? rsqrtf((float)s3) : 0.f;
                           offs2[n0+3] = make_int2(lo + e3, lo + e3 + s3); }
    __syncthreads();
    for (int k = lo + t; k < hi; k += 256) {
        unsigned u = pairs[k];
        int pos = lo + atomicAdd(&cur[u >> 20], 1);
        sr[pos] = (int)(u & 0xFFFFFu);
    }
}

// ===================== main phase =====================

// --- init: layer-0 fp32 (nt) + prescaled bf16 mirror -------------------------
__global__ void k_init(const float4* __restrict__ user, const float4* __restrict__ item,
                       float4* __restrict__ all_emb, const float* __restrict__ dinv,
                       uint4* __restrict__ xb0) {
    int tid = blockIdx.x * blockDim.x + threadIdx.x;
    if (tid >= NNODES * 8) return;
    int n    = tid >> 3;
    int lane = tid & 7;
    const float4* s = ((n < NUSERS) ? user + (size_t)n * 16
                                    : item + (size_t)(n - NUSERS) * 16) + lane * 2;
    float4 a = s[0], b = s[1];
    f4* dst = reinterpret_cast<f4*>(all_emb + (size_t)n * 64 + lane * 2);
    f4 av = {a.x, a.y, a.z, a.w};
    f4 bv = {b.x, b.y, b.z, b.w};
    __builtin_nontemporal_store(av, dst + 0);
    __builtin_nontemporal_store(bv, dst + 1);
    float dv = dinv[n];
    uint4 o;
    o.x = packbf(dv * a.x, dv * a.y); o.y = packbf(dv * a.z, dv * a.w);
    o.z = packbf(dv * b.x, dv * b.y); o.w = packbf(dv * b.z, dv * b.w);
    xb0[(size_t)n * 8 + lane] = o;
}

// --- propagate layer L: bf16 gather (prescaled), fp32 accumulate -------------
template <int L, bool FUSE_OUT>
__global__ void k_prop(const int2* __restrict__ offs2,
                       const int* __restrict__ sr, const float* __restrict__ dinv,
                       const uint4* __restrict__ xbp,
                       uint4* __restrict__ xbc,
                       float4* __restrict__ all_emb,
                       float* __restrict__ out_users, float* __restrict__ out_items) {
    int tid = blockIdx.x * blockDim.x + threadIdx.x;
    if (tid >= NNODES * 8) return;
    int n    = tid >> 3;
    int lane = tid & 7;
    int2 be = offs2[n];
    int b = be.x, e = be.y;
    float4 accA = make_float4(0.f, 0.f, 0.f, 0.f);
    float4 accB = make_float4(0.f, 0.f, 0.f, 0.f);
    const uint4* src = xbp + lane;

    int k = b;
    for (; k + 4 <= e; k += 4) {
        int r0 = sr[k + 0], r1 = sr[k + 1], r2 = sr[k + 2], r3 = sr[k + 3];
        uint4 q0 = src[(size_t)r0 * 8];
        uint4 q1 = src[(size_t)r1 * 8];
        uint4 q2 = src[(size_t)r2 * 8];
        uint4 q3 = src[(size_t)r3 * 8];
        acc8(accA, accB, q0); acc8(accA, accB, q1);
        acc8(accA, accB, q2); acc8(accA, accB, q3);
    }
    for (; k < e; ++k) {
        uint4 q = src[(size_t)sr[k] * 8];
        acc8(accA, accB, q);
    }
    float dv = dinv[n];
    accA.x *= dv; accA.y *= dv; accA.z *= dv; accA.w *= dv;
    accB.x *= dv; accB.y *= dv; accB.z *= dv; accB.w *= dv;

    f4 aA = {accA.x, accA.y, accA.z, accA.w};
    f4 aB = {accB.x, accB.y, accB.z, accB.w};
    f4* dstn = reinterpret_cast<f4*>(all_emb + (size_t)n * 64 + L * 16 + lane * 2);
    __builtin_nontemporal_store(aA, dstn + 0);
    __builtin_nontemporal_store(aB, dstn + 1);

    if constexpr (!FUSE_OUT) {
        uint4 o;
        o.x = packbf(dv * accA.x, dv * accA.y);
        o.y = packbf(dv * accA.z, dv * accA.w);
        o.z = packbf(dv * accB.x, dv * accB.y);
        o.w = packbf(dv * accB.z, dv * accB.w);
        xbc[(size_t)n * 8 + lane] = o;
    } else {
        const f4* p = reinterpret_cast<const f4*>(all_emb + (size_t)n * 64 + lane * 2);
        f4 x0a = __builtin_nontemporal_load(p + 0);
        f4 x0b = __builtin_nontemporal_load(p + 1);
        f4 x1a = __builtin_nontemporal_load(p + 16);
        f4 x1b = __builtin_nontemporal_load(p + 17);
        f4 x2a = __builtin_nontemporal_load(p + 32);
        f4 x2b = __builtin_nontemporal_load(p + 33);
        f4 ma = (x0a + x1a + x2a + aA) * 0.25f;
        f4 mb = (x0b + x1b + x2b + aB) * 0.25f;
        if (n < NUSERS) {
            f4* ou = reinterpret_cast<f4*>(out_users + (size_t)n * 64 + lane * 8);
            __builtin_nontemporal_store(ma, ou + 0);
            __builtin_nontemporal_store(mb, ou + 1);
        }
        if (n >= NITEMS) {
            f4* oi = reinterpret_cast<f4*>(out_items + (size_t)(n - NITEMS) * 64 + lane * 8);
            __builtin_nontemporal_store(ma, oi + 0);
            __builtin_nontemporal_store(mb, oi + 1);
        }
    }
}

extern "C" void kernel_launch(void* const* d_in, const int* in_sizes, int n_in,
                              void* d_out, int out_size, void* d_ws, size_t ws_size,
                              hipStream_t stream) {
    const float* user  = (const float*)d_in[0];
    const float* item  = (const float*)d_in[1];
    const int*   edges = (const int*)d_in[2];
    const int*   row = edges;            // edge_index[0]
    const int*   col = edges + NE;       // edge_index[1]

    float* out       = (float*)d_out;
    float* out_users = out;
    float* out_items = out + (size_t)NUSERS * 64;
    float* all_emb   = out + (size_t)NUSERS * 64 * 2;   // [700000][4][64]

    // workspace carve (~228 MB)
    char* ws = (char*)d_ws;
    uint4*    xb0   = (uint4*)ws;                     ws += (size_t)NNODES * 128;
    uint4*    xb1   = (uint4*)ws;                     ws += (size_t)NNODES * 128;
    unsigned* pairs = (unsigned*)ws;                  ws += (size_t)NE * 4;
    int*      sr    = (int*)ws;                       ws += (size_t)NE * 4;
    int2*     offs2 = (int2*)ws;                      ws += (size_t)NNODES * 8;
    float*    dinv  = (float*)ws;                     ws += (size_t)NNODES * 4;
    int*      bcnt  = (int*)ws;                       ws += (size_t)NB * 4;
    int*      bbase = (int*)ws;                       ws += (size_t)(NB + 1) * 4;
    int*      bcur  = (int*)ws;                       ws += (size_t)NB * 4;

    const int B = 256;
    const int prop_grid = (NNODES * 8 + B - 1) / B;

    (void)hipMemsetAsync(bcnt, 0, (size_t)NB * sizeof(int), stream);
    k_bcount<<<1024, 256, 0, stream>>>(col, bcnt);
    k_bscan <<<1, 1024, 0, stream>>>(bcnt, bbase, bcur);
    k_bpart <<<(NE + CH - 1) / CH, 256, 0, stream>>>(row, col, bcur, pairs);
    k_bsort <<<NB, 256, 0, stream>>>(pairs, bbase, sr, dinv, offs2);
    k_init  <<<prop_grid, B, 0, stream>>>(
        (const float4*)user, (const float4*)item, (float4*)all_emb, dinv, xb0);

    k_prop<1, false><<<prop_grid, B, 0, stream>>>(offs2, sr, dinv, xb0, xb1,
                                                  (float4*)all_emb, nullptr, nullptr);
    k_prop<2, false><<<prop_grid, B, 0, stream>>>(offs2, sr, dinv, xb1, xb0,
                                                  (float4*)all_emb, nullptr, nullptr);
    k_prop<3, true> <<<prop_grid, B, 0, stream>>>(offs2, sr, dinv, xb0, nullptr,
                                                  (float4*)all_emb, out_users, out_items);
}